// Round 12
// baseline (258.046 us; speedup 1.0000x reference)
//
#include <hip/hip_runtime.h>
#include <stdint.h>

namespace {
constexpr int kB  = 16384;
constexpr int kN  = 128;
constexpr int kI  = 3;
constexpr int kC  = 4;
constexpr int kH  = 90;
constexpr int kL  = 3;
constexpr int BT  = 32;     // batch rows per block (1 wave, 2 n-tiles)
constexpr int NT  = 2;      // n-tiles of 16
constexpr int KP  = 96;
// A-fragment-contiguous weight tile: 18 frag-blocks (fb=ks*6+mt) x 1024 B.
constexpr int TILE_USH = 18 * 512;
constexpr size_t WT_BYTES = (size_t)4 * kN * TILE_USH * 2;   // 9,437,184
constexpr size_t WO_OFF   = WT_BYTES;                        // float wo[128][96]
constexpr size_t XK_OFF   = WO_OFF + (size_t)kN * KP * 4;    // ushort xk[384][16384]
constexpr size_t OT_OFF   = XK_OFF + (size_t)kN * kI * kB * 2; // float outT[128][16384]
}

typedef __attribute__((ext_vector_type(8))) short bf16x8;
typedef __attribute__((ext_vector_type(4))) float f32x4;

__device__ __forceinline__ uint32_t pack_bf16(float lo, float hi) {
#if __has_builtin(__builtin_amdgcn_cvt_pk_bf16_f32)
  auto r = __builtin_amdgcn_cvt_pk_bf16_f32(lo, hi);
  union { decltype(r) v; uint32_t u; } c; c.v = r; return c.u;
#else
  // round-half-up to bf16 then byte-merge: 3 VALU (add, add, v_perm_b32)
  union { float f; uint32_t i; } a, b; a.f = lo; b.f = hi;
  uint32_t ua = a.i + 0x8000u;
  uint32_t ub = b.i + 0x8000u;
  return __builtin_amdgcn_perm(ub, ua, 0x07060302);  // {ub[3:2], ua[3:2]}
#endif
}
__device__ __forceinline__ ushort f2bf(float f) {
  union { float f; uint32_t i; } v; v.f = f;
  uint32_t u = v.i + 0x7FFFu + ((v.i >> 16) & 1u);
  return (ushort)(u >> 16);
}

// ---- merged preprocess, fully vectorized emission (dwordx4 stores) ----
__global__ __launch_bounds__(256) void prep_kernel(
    const float* __restrict__ x,
    const float* __restrict__ W_in, const float* __restrict__ b_in,
    const float* __restrict__ W_hid, const float* __restrict__ b_hid,
    const float* __restrict__ W_out, const float* __restrict__ b_out,
    ushort* __restrict__ wt, float* __restrict__ wo, ushort* __restrict__ xk)
{
  __shared__ float smem[kH * (kH + 1) + kH];
  const int tid = threadIdx.x;
  const int bid = blockIdx.x;

  if (bid < 4 * kN) {          // ---- weight tiles, A-frag-contiguous ----
    float* ldsw = smem;                      // [k][j], stride kH+1 = 91
    float* ldsb = smem + kH * (kH + 1);
    const int node  = bid & (kN - 1);
    const int layer = bid >> 7;
    const int ksrc  = (layer == 0) ? (kI + kC) : kH;
    const float* src;
    const float* bsrc;
    if (layer == 0) { src = W_in + (size_t)node * (kI + kC) * kH; bsrc = b_in + (size_t)node * kH; }
    else {
      int l = layer - 1;
      src  = W_hid + (size_t)(l * kN + node) * kH * kH;
      bsrc = b_hid + (size_t)(l * kN + node) * kH;
    }
    for (int idx = tid; idx < ksrc * kH; idx += 256)
      ldsw[(idx / kH) * (kH + 1) + (idx % kH)] = src[idx];
    if (tid < kH) ldsb[tid] = bsrc[tid];
    __syncthreads();
    ushort* dst = wt + (size_t)bid * TILE_USH;
    const int nch = (layer == 0) ? 384 : 1152;   // 16B chunks (fb*64 + lane)
#pragma unroll
    for (int it = 0; it < 5; ++it) {
      int c = tid + it * 256;
      if (c < nch) {
        int fb = c >> 6, lane = c & 63;
        int mt = fb % 6, ks = fb / 6;
        int j = mt * 16 + (lane & 15);
        int kb = ks * 32 + (lane >> 4) * 8;
        float v[8];
#pragma unroll
        for (int i = 0; i < 8; ++i) {
          int k = kb + i;
          float t = 0.f;
          if (j < kH) {
            if (k < ksrc)       t = ldsw[k * (kH + 1) + j];
            else if (k == ksrc) t = ldsb[j];
          }
          v[i] = t;
        }
        uint4 p;
        p.x = pack_bf16(v[0], v[1]); p.y = pack_bf16(v[2], v[3]);
        p.z = pack_bf16(v[4], v[5]); p.w = pack_bf16(v[6], v[7]);
        *(uint4*)&dst[(size_t)c * 8] = p;
      }
    }
  } else if (bid < 4 * kN + 4) {   // ---- wout float image ----
    int base = (bid - 4 * kN) * 3072;
    for (int t = 0; t < 12; ++t) {
      int idx = base + t * 256 + tid;
      int node = idx / KP, j = idx % KP;
      float v = 0.f;
      if (j < kH)       v = W_out[node * kH + j];
      else if (j == kH) v = b_out[node];
      wo[idx] = v;
    }
  } else {                         // ---- x transpose -> xk[384][16384] bf16 ----
    int xb = bid - (4 * kN + 4);
    int b0 = (xb & 255) * 64;
    int c0 = (xb >> 8) * 96;
    float* lds = smem;             // [64][97]
    for (int idx = tid; idx < 64 * 96; idx += 256) {
      int r = idx / 96, c = idx % 96;
      lds[r * 97 + c] = x[(size_t)(b0 + r) * (kN * kI) + c0 + c];
    }
    __syncthreads();
#pragma unroll
    for (int it = 0; it < 3; ++it) {            // 96 rows x 8 chunks = 768
      int c = tid + it * 256;
      int nk = c >> 3, b = (c & 7) * 8;
      float v[8];
#pragma unroll
      for (int i = 0; i < 8; ++i) v[i] = lds[(b + i) * 97 + nk];
      uint4 p;
      p.x = pack_bf16(v[0], v[1]); p.y = pack_bf16(v[2], v[3]);
      p.z = pack_bf16(v[4], v[5]); p.w = pack_bf16(v[6], v[7]);
      *(uint4*)&xk[(size_t)(c0 + nk) * kB + b0 + b] = p;
    }
  }
}

// ---- main: 1 wave/block, 32 batch rows (2 n-tiles), barrier-free.
// acc 6x2 f32x4 = 48 regs -> launch_bounds(64,4) = 4 waves/SIMD.
__global__ __launch_bounds__(64, 4) void dnpu_kernel(
    const ushort* __restrict__ xk, const float* __restrict__ controls,
    const ushort* __restrict__ wt, const float* __restrict__ wo,
    float* __restrict__ outT)
{
  __shared__ __align__(16) ushort fbuf[12][BT][8];   // 6,144 B

  const int lane = threadIdx.x;
  const int node = (int)(blockIdx.x >> 9);           // co-resident blocks share a node
  const int m0   = (int)(blockIdx.x & 511) * BT;
  const int quad = lane >> 4;
  const int l16  = lane & 15;

  const f32x4 zf = (f32x4){0.f, 0.f, 0.f, 0.f};      // zero C operand
  f32x4 acc[6][NT];

  // ---- layer0 B-frags in registers: only quad==0 lanes non-zero ----
  bf16x8 bfr0[NT];
  {
    const ushort cb0 = f2bf(controls[node * kC + 0]);
    const ushort cb1 = f2bf(controls[node * kC + 1]);
    const ushort cb2 = f2bf(controls[node * kC + 2]);
    const ushort cb3 = f2bf(controls[node * kC + 3]);
    if (quad == 0) {
      const ushort* x0p = xk + (size_t)(node * kI + 0) * kB + m0 + l16;
      const ushort* x1p = xk + (size_t)(node * kI + 1) * kB + m0 + l16;
      const ushort* x2p = xk + (size_t)(node * kI + 2) * kB + m0 + l16;
#pragma unroll
      for (int nt = 0; nt < NT; ++nt) {
        union { ushort s[8]; bf16x8 v; } f;
        f.s[0] = x0p[nt * 16]; f.s[1] = x1p[nt * 16]; f.s[2] = x2p[nt * 16];
        f.s[3] = cb0; f.s[4] = cb1; f.s[5] = cb2; f.s[6] = cb3;
        f.s[7] = 0x3F80;                       // 1.0 (bias row k=7)
        bfr0[nt] = f.v;
      }
    } else {
#pragma unroll
      for (int nt = 0; nt < NT; ++nt)
        bfr0[nt] = (bf16x8){0,0,0,0,0,0,0,0};
    }
  }

  // ---- layer0 gemm: C = zf, A-frag streamed per mt ----
  {
    const ushort* tl = wt + (size_t)(0 * kN + node) * TILE_USH;
#pragma unroll
    for (int mt = 0; mt < 6; ++mt) {
      bf16x8 afr = *(const bf16x8*)&tl[(size_t)mt * 512 + lane * 8];
#pragma unroll
      for (int nt = 0; nt < NT; ++nt)
        acc[mt][nt] = __builtin_amdgcn_mfma_f32_16x16x32_bf16(afr, bfr0[nt], zf, 0, 0, 0);
    }
  }

  // relu(acc) -> fbuf (k-major frag layout); j_out==90 := 1.0 (next bias row)
  auto write_h = [&]() {
#pragma unroll
    for (int mt = 0; mt < 6; ++mt) {
      const int kb = 2 * mt + (quad >> 1);
      const int i0 = (quad & 1) * 4;
#pragma unroll
      for (int nt = 0; nt < NT; ++nt) {
        float v0 = fmaxf(acc[mt][nt][0], 0.f);
        float v1 = fmaxf(acc[mt][nt][1], 0.f);
        float v2 = fmaxf(acc[mt][nt][2], 0.f);
        float v3 = fmaxf(acc[mt][nt][3], 0.f);
        if (mt == 5 && quad == 2) v2 = 1.0f;   // j_out = 90
        uint2 p;
        p.x = pack_bf16(v0, v1);
        p.y = pack_bf16(v2, v3);
        *(uint2*)&fbuf[kb][nt * 16 + l16][i0] = p;
      }
    }
  };

#pragma unroll
  for (int l = 0; l < kL; ++l) {
    const ushort* tl = wt + (size_t)((l + 1) * kN + node) * TILE_USH;
    write_h();

    // ks = 0: C = zf (no zero-init of acc), A streamed per mt
    {
      bf16x8 bfr[NT];
#pragma unroll
      for (int nt = 0; nt < NT; ++nt)
        bfr[nt] = *(const bf16x8*)&fbuf[quad][nt * 16 + l16][0];
#pragma unroll
      for (int mt = 0; mt < 6; ++mt) {
        bf16x8 afr = *(const bf16x8*)&tl[(size_t)mt * 512 + lane * 8];
#pragma unroll
        for (int nt = 0; nt < NT; ++nt)
          acc[mt][nt] = __builtin_amdgcn_mfma_f32_16x16x32_bf16(afr, bfr[nt], zf, 0, 0, 0);
      }
    }
#pragma unroll
    for (int ks = 1; ks < 3; ++ks) {
      bf16x8 bfr[NT];
#pragma unroll
      for (int nt = 0; nt < NT; ++nt)
        bfr[nt] = *(const bf16x8*)&fbuf[ks * 4 + quad][nt * 16 + l16][0];
#pragma unroll
      for (int mt = 0; mt < 6; ++mt) {
        bf16x8 afr = *(const bf16x8*)&tl[(size_t)(ks * 6 + mt) * 512 + lane * 8];
#pragma unroll
        for (int nt = 0; nt < NT; ++nt)
          acc[mt][nt] = __builtin_amdgcn_mfma_f32_16x16x32_bf16(afr, bfr[nt], acc[mt][nt], 0, 0, 0);
      }
    }
  }

  // ---- final dot in registers: out = relu(h3) . wout (+ b_out via j=90) ----
  {
    float s[NT] = {0.f, 0.f};
#pragma unroll
    for (int mt = 0; mt < 6; ++mt) {
      float4 wof = *(const float4*)&wo[node * KP + mt * 16 + quad * 4];
#pragma unroll
      for (int nt = 0; nt < NT; ++nt) {
        float h0 = fmaxf(acc[mt][nt][0], 0.f);
        float h1 = fmaxf(acc[mt][nt][1], 0.f);
        float h2 = fmaxf(acc[mt][nt][2], 0.f);
        float h3 = fmaxf(acc[mt][nt][3], 0.f);
        if (mt == 5 && quad == 2) h2 = 1.0f;   // j=90 pairs with wout[90]=b_out
        s[nt] += h0 * wof.x + h1 * wof.y + h2 * wof.z + h3 * wof.w;
      }
    }
#pragma unroll
    for (int nt = 0; nt < NT; ++nt) {
      s[nt] += __shfl_xor(s[nt], 16);
      s[nt] += __shfl_xor(s[nt], 32);
    }
    if (quad < NT) {
      float r = (quad == 0) ? s[0] : s[1];
      outT[(size_t)node * kB + m0 + quad * 16 + l16] = r;  // 128 B contiguous
    }
  }
}

// ---- outT [128][16384] -> out [16384][128], LDS-tiled, coalesced both sides ----
__global__ __launch_bounds__(256) void transpose_out(
    const float* __restrict__ ot, float* __restrict__ out)
{
  __shared__ float t[64][65];
  const int b0 = (int)(blockIdx.x & 255) * 64;
  const int n0 = (int)(blockIdx.x >> 8) * 64;
  const int c  = threadIdx.x & 63;
  const int r4 = threadIdx.x >> 6;
#pragma unroll
  for (int i = 0; i < 16; ++i) {
    int n = r4 + i * 4;
    t[n][c] = ot[(size_t)(n0 + n) * kB + b0 + c];
  }
  __syncthreads();
#pragma unroll
  for (int i = 0; i < 16; ++i) {
    int b = r4 + i * 4;
    out[(size_t)(b0 + b) * kN + n0 + c] = t[c][b];
  }
}

extern "C" void kernel_launch(void* const* d_in, const int* in_sizes, int n_in,
                              void* d_out, int out_size, void* d_ws, size_t ws_size,
                              hipStream_t stream) {
  const float* x        = (const float*)d_in[0];
  const float* controls = (const float*)d_in[1];
  const float* W_in     = (const float*)d_in[2];
  const float* b_in     = (const float*)d_in[3];
  const float* W_hid    = (const float*)d_in[4];
  const float* b_hid    = (const float*)d_in[5];
  const float* W_out    = (const float*)d_in[6];
  const float* b_out    = (const float*)d_in[7];
  float* out = (float*)d_out;

  ushort* wt = (ushort*)d_ws;
  float*  wo = (float*)((char*)d_ws + WO_OFF);
  ushort* xk = (ushort*)((char*)d_ws + XK_OFF);
  float*  ot = (float*)((char*)d_ws + OT_OFF);

  hipLaunchKernelGGL(prep_kernel, dim3(4 * kN + 4 + 1024), dim3(256), 0, stream,
                     x, W_in, b_in, W_hid, b_hid, W_out, b_out, wt, wo, xk);

  dim3 grid(kN * (kB / BT));   // bid = node*512 + tile -> 65536 one-wave blocks
  hipLaunchKernelGGL(dnpu_kernel, grid, dim3(64), 0, stream,
                     xk, controls, wt, wo, ot);

  hipLaunchKernelGGL(transpose_out, dim3(512), dim3(256), 0, stream, ot, out);
}

// Round 13
// 238.506 us; speedup vs baseline: 1.0819x; 1.0819x over previous
//
#include <hip/hip_runtime.h>
#include <stdint.h>

namespace {
constexpr int kB  = 16384;
constexpr int kN  = 128;
constexpr int kI  = 3;
constexpr int kC  = 4;
constexpr int kH  = 90;
constexpr int kL  = 3;
constexpr int BT  = 64;     // batch rows per block (1 wave, 4 n-tiles)
constexpr int KP  = 96;
// A-fragment-contiguous weight tile: 18 frag-blocks (fb=ks*6+mt) x 1024 B.
constexpr int TILE_USH = 18 * 512;
constexpr size_t WT_BYTES = (size_t)4 * kN * TILE_USH * 2;   // 9,437,184
constexpr size_t WO_OFF   = WT_BYTES;                        // float wo[128][96]
constexpr size_t XK_OFF   = WO_OFF + (size_t)kN * KP * 4;    // ushort xk[384][16384]
constexpr size_t OT_OFF   = XK_OFF + (size_t)kN * kI * kB * 2; // float outT[128][16384]
}

typedef __attribute__((ext_vector_type(8))) short bf16x8;
typedef __attribute__((ext_vector_type(4))) float f32x4;

__device__ __forceinline__ uint32_t pack_bf16(float lo, float hi) {
#if __has_builtin(__builtin_amdgcn_cvt_pk_bf16_f32)
  auto r = __builtin_amdgcn_cvt_pk_bf16_f32(lo, hi);
  union { decltype(r) v; uint32_t u; } c; c.v = r; return c.u;
#else
  // round-half-up to bf16 then byte-merge: 3 VALU (add, add, v_perm_b32)
  union { float f; uint32_t i; } a, b; a.f = lo; b.f = hi;
  uint32_t ua = a.i + 0x8000u;
  uint32_t ub = b.i + 0x8000u;
  return __builtin_amdgcn_perm(ub, ua, 0x07060302);  // {ub[3:2], ua[3:2]}
#endif
}
__device__ __forceinline__ ushort f2bf(float f) {
  union { float f; uint32_t i; } v; v.f = f;
  uint32_t u = v.i + 0x7FFFu + ((v.i >> 16) & 1u);
  return (ushort)(u >> 16);
}

// ---- merged preprocess, vectorized emission (round-12, kept) ----
__global__ __launch_bounds__(256) void prep_kernel(
    const float* __restrict__ x,
    const float* __restrict__ W_in, const float* __restrict__ b_in,
    const float* __restrict__ W_hid, const float* __restrict__ b_hid,
    const float* __restrict__ W_out, const float* __restrict__ b_out,
    ushort* __restrict__ wt, float* __restrict__ wo, ushort* __restrict__ xk)
{
  __shared__ float smem[kH * (kH + 1) + kH];
  const int tid = threadIdx.x;
  const int bid = blockIdx.x;

  if (bid < 4 * kN) {          // ---- weight tiles, A-frag-contiguous ----
    float* ldsw = smem;                      // [k][j], stride kH+1 = 91
    float* ldsb = smem + kH * (kH + 1);
    const int node  = bid & (kN - 1);
    const int layer = bid >> 7;
    const int ksrc  = (layer == 0) ? (kI + kC) : kH;
    const float* src;
    const float* bsrc;
    if (layer == 0) { src = W_in + (size_t)node * (kI + kC) * kH; bsrc = b_in + (size_t)node * kH; }
    else {
      int l = layer - 1;
      src  = W_hid + (size_t)(l * kN + node) * kH * kH;
      bsrc = b_hid + (size_t)(l * kN + node) * kH;
    }
    for (int idx = tid; idx < ksrc * kH; idx += 256)
      ldsw[(idx / kH) * (kH + 1) + (idx % kH)] = src[idx];
    if (tid < kH) ldsb[tid] = bsrc[tid];
    __syncthreads();
    ushort* dst = wt + (size_t)bid * TILE_USH;
    const int nch = (layer == 0) ? 384 : 1152;   // 16B chunks (fb*64 + lane)
#pragma unroll
    for (int it = 0; it < 5; ++it) {
      int c = tid + it * 256;
      if (c < nch) {
        int fb = c >> 6, lane = c & 63;
        int mt = fb % 6, ks = fb / 6;
        int j = mt * 16 + (lane & 15);
        int kb = ks * 32 + (lane >> 4) * 8;
        float v[8];
#pragma unroll
        for (int i = 0; i < 8; ++i) {
          int k = kb + i;
          float t = 0.f;
          if (j < kH) {
            if (k < ksrc)       t = ldsw[k * (kH + 1) + j];
            else if (k == ksrc) t = ldsb[j];
          }
          v[i] = t;
        }
        uint4 p;
        p.x = pack_bf16(v[0], v[1]); p.y = pack_bf16(v[2], v[3]);
        p.z = pack_bf16(v[4], v[5]); p.w = pack_bf16(v[6], v[7]);
        *(uint4*)&dst[(size_t)c * 8] = p;
      }
    }
  } else if (bid < 4 * kN + 4) {   // ---- wout float image ----
    int base = (bid - 4 * kN) * 3072;
    for (int t = 0; t < 12; ++t) {
      int idx = base + t * 256 + tid;
      int node = idx / KP, j = idx % KP;
      float v = 0.f;
      if (j < kH)       v = W_out[node * kH + j];
      else if (j == kH) v = b_out[node];
      wo[idx] = v;
    }
  } else {                         // ---- x transpose -> xk[384][16384] bf16 ----
    int xb = bid - (4 * kN + 4);
    int b0 = (xb & 255) * 64;
    int c0 = (xb >> 8) * 96;
    float* lds = smem;             // [64][97]
    for (int idx = tid; idx < 64 * 96; idx += 256) {
      int r = idx / 96, c = idx % 96;
      lds[r * 97 + c] = x[(size_t)(b0 + r) * (kN * kI) + c0 + c];
    }
    __syncthreads();
#pragma unroll
    for (int it = 0; it < 3; ++it) {            // 96 rows x 8 chunks = 768
      int c = tid + it * 256;
      int nk = c >> 3, b = (c & 7) * 8;
      float v[8];
#pragma unroll
      for (int i = 0; i < 8; ++i) v[i] = lds[(b + i) * 97 + nk];
      uint4 p;
      p.x = pack_bf16(v[0], v[1]); p.y = pack_bf16(v[2], v[3]);
      p.z = pack_bf16(v[4], v[5]); p.w = pack_bf16(v[6], v[7]);
      *(uint4*)&xk[(size_t)(c0 + nk) * kB + b0 + b] = p;
    }
  }
}

// ---- main: round-11 structure (empirical best): BT=64, 1 wave/block,
// barrier-free, A-frags streamed per mt, launch_bounds(64,3).
__global__ __launch_bounds__(64, 3) void dnpu_kernel(
    const ushort* __restrict__ xk, const float* __restrict__ controls,
    const ushort* __restrict__ wt, const float* __restrict__ wo,
    float* __restrict__ outT)
{
  __shared__ __align__(16) ushort fbuf[12][BT][8];   // 12,288 B

  const int lane = threadIdx.x;
  const int node = (int)(blockIdx.x >> 8);           // co-resident blocks share a node
  const int m0   = (int)(blockIdx.x & 255) * BT;
  const int quad = lane >> 4;
  const int l16  = lane & 15;

  const f32x4 zf = (f32x4){0.f, 0.f, 0.f, 0.f};      // zero C operand
  f32x4 acc[6][4];

  // ---- layer0 B-frags in registers: only quad==0 lanes non-zero ----
  bf16x8 bfr0[4];
  {
    const ushort cb0 = f2bf(controls[node * kC + 0]);
    const ushort cb1 = f2bf(controls[node * kC + 1]);
    const ushort cb2 = f2bf(controls[node * kC + 2]);
    const ushort cb3 = f2bf(controls[node * kC + 3]);
    if (quad == 0) {
      const ushort* x0p = xk + (size_t)(node * kI + 0) * kB + m0 + l16;
      const ushort* x1p = xk + (size_t)(node * kI + 1) * kB + m0 + l16;
      const ushort* x2p = xk + (size_t)(node * kI + 2) * kB + m0 + l16;
#pragma unroll
      for (int nt = 0; nt < 4; ++nt) {
        union { ushort s[8]; bf16x8 v; } f;
        f.s[0] = x0p[nt * 16]; f.s[1] = x1p[nt * 16]; f.s[2] = x2p[nt * 16];
        f.s[3] = cb0; f.s[4] = cb1; f.s[5] = cb2; f.s[6] = cb3;
        f.s[7] = 0x3F80;                       // 1.0 (bias row k=7)
        bfr0[nt] = f.v;
      }
    } else {
#pragma unroll
      for (int nt = 0; nt < 4; ++nt)
        bfr0[nt] = (bf16x8){0,0,0,0,0,0,0,0};
    }
  }

  // ---- layer0 gemm: C = zf (defined), A-frag streamed per mt ----
  {
    const ushort* tl = wt + (size_t)(0 * kN + node) * TILE_USH;
#pragma unroll
    for (int mt = 0; mt < 6; ++mt) {
      bf16x8 afr = *(const bf16x8*)&tl[(size_t)mt * 512 + lane * 8];
#pragma unroll
      for (int nt = 0; nt < 4; ++nt)
        acc[mt][nt] = __builtin_amdgcn_mfma_f32_16x16x32_bf16(afr, bfr0[nt], zf, 0, 0, 0);
    }
  }

  // relu(acc) -> fbuf (k-major frag layout); j_out==90 := 1.0 (next bias row)
  auto write_h = [&]() {
#pragma unroll
    for (int mt = 0; mt < 6; ++mt) {
      const int kb = 2 * mt + (quad >> 1);
      const int i0 = (quad & 1) * 4;
#pragma unroll
      for (int nt = 0; nt < 4; ++nt) {
        float v0 = fmaxf(acc[mt][nt][0], 0.f);
        float v1 = fmaxf(acc[mt][nt][1], 0.f);
        float v2 = fmaxf(acc[mt][nt][2], 0.f);
        float v3 = fmaxf(acc[mt][nt][3], 0.f);
        if (mt == 5 && quad == 2) v2 = 1.0f;   // j_out = 90
        uint2 p;
        p.x = pack_bf16(v0, v1);
        p.y = pack_bf16(v2, v3);
        *(uint2*)&fbuf[kb][nt * 16 + l16][i0] = p;
      }
    }
  };

#pragma unroll
  for (int l = 0; l < kL; ++l) {
    const ushort* tl = wt + (size_t)((l + 1) * kN + node) * TILE_USH;
    write_h();

    // ks = 0: C = zf (no zero-init of acc), A streamed per mt
    {
      bf16x8 bfr[4];
#pragma unroll
      for (int nt = 0; nt < 4; ++nt)
        bfr[nt] = *(const bf16x8*)&fbuf[quad][nt * 16 + l16][0];
#pragma unroll
      for (int mt = 0; mt < 6; ++mt) {
        bf16x8 afr = *(const bf16x8*)&tl[(size_t)mt * 512 + lane * 8];
#pragma unroll
        for (int nt = 0; nt < 4; ++nt)
          acc[mt][nt] = __builtin_amdgcn_mfma_f32_16x16x32_bf16(afr, bfr[nt], zf, 0, 0, 0);
      }
    }
#pragma unroll
    for (int ks = 1; ks < 3; ++ks) {
      bf16x8 bfr[4];
#pragma unroll
      for (int nt = 0; nt < 4; ++nt)
        bfr[nt] = *(const bf16x8*)&fbuf[ks * 4 + quad][nt * 16 + l16][0];
#pragma unroll
      for (int mt = 0; mt < 6; ++mt) {
        bf16x8 afr = *(const bf16x8*)&tl[(size_t)(ks * 6 + mt) * 512 + lane * 8];
#pragma unroll
        for (int nt = 0; nt < 4; ++nt)
          acc[mt][nt] = __builtin_amdgcn_mfma_f32_16x16x32_bf16(afr, bfr[nt], acc[mt][nt], 0, 0, 0);
      }
    }
  }

  // ---- final dot in registers: out = relu(h3) . wout (+ b_out via j=90) ----
  {
    // hoist the 6 wout loads so they issue as one clustered vmcnt batch
    float4 wof[6];
#pragma unroll
    for (int mt = 0; mt < 6; ++mt)
      wof[mt] = *(const float4*)&wo[node * KP + mt * 16 + quad * 4];
    float s[4] = {0.f, 0.f, 0.f, 0.f};
#pragma unroll
    for (int mt = 0; mt < 6; ++mt) {
#pragma unroll
      for (int nt = 0; nt < 4; ++nt) {
        float h0 = fmaxf(acc[mt][nt][0], 0.f);
        float h1 = fmaxf(acc[mt][nt][1], 0.f);
        float h2 = fmaxf(acc[mt][nt][2], 0.f);
        float h3 = fmaxf(acc[mt][nt][3], 0.f);
        if (mt == 5 && quad == 2) h2 = 1.0f;   // j=90 pairs with wout[90]=b_out
        s[nt] += h0 * wof[mt].x + h1 * wof[mt].y + h2 * wof[mt].z + h3 * wof[mt].w;
      }
    }
#pragma unroll
    for (int nt = 0; nt < 4; ++nt) {
      s[nt] += __shfl_xor(s[nt], 16);
      s[nt] += __shfl_xor(s[nt], 32);
    }
    float r = (quad == 0) ? s[0] : (quad == 1) ? s[1] : (quad == 2) ? s[2] : s[3];
    outT[(size_t)node * kB + m0 + lane] = r;   // lane-linear, 256 B contiguous
  }
}

// ---- outT [128][16384] -> out [16384][128], LDS-tiled, coalesced both sides ----
__global__ __launch_bounds__(256) void transpose_out(
    const float* __restrict__ ot, float* __restrict__ out)
{
  __shared__ float t[64][65];
  const int b0 = (int)(blockIdx.x & 255) * 64;
  const int n0 = (int)(blockIdx.x >> 8) * 64;
  const int c  = threadIdx.x & 63;
  const int r4 = threadIdx.x >> 6;
#pragma unroll
  for (int i = 0; i < 16; ++i) {
    int n = r4 + i * 4;
    t[n][c] = ot[(size_t)(n0 + n) * kB + b0 + c];
  }
  __syncthreads();
#pragma unroll
  for (int i = 0; i < 16; ++i) {
    int b = r4 + i * 4;
    out[(size_t)(b0 + b) * kN + n0 + c] = t[c][b];
  }
}

extern "C" void kernel_launch(void* const* d_in, const int* in_sizes, int n_in,
                              void* d_out, int out_size, void* d_ws, size_t ws_size,
                              hipStream_t stream) {
  const float* x        = (const float*)d_in[0];
  const float* controls = (const float*)d_in[1];
  const float* W_in     = (const float*)d_in[2];
  const float* b_in     = (const float*)d_in[3];
  const float* W_hid    = (const float*)d_in[4];
  const float* b_hid    = (const float*)d_in[5];
  const float* W_out    = (const float*)d_in[6];
  const float* b_out    = (const float*)d_in[7];
  float* out = (float*)d_out;

  ushort* wt = (ushort*)d_ws;
  float*  wo = (float*)((char*)d_ws + WO_OFF);
  ushort* xk = (ushort*)((char*)d_ws + XK_OFF);
  float*  ot = (float*)((char*)d_ws + OT_OFF);

  hipLaunchKernelGGL(prep_kernel, dim3(4 * kN + 4 + 1024), dim3(256), 0, stream,
                     x, W_in, b_in, W_hid, b_hid, W_out, b_out, wt, wo, xk);

  dim3 grid(kN * (kB / BT));   // bid = node*256 + tile -> 32768 one-wave blocks
  hipLaunchKernelGGL(dnpu_kernel, grid, dim3(64), 0, stream,
                     xk, controls, wt, wo, ot);

  hipLaunchKernelGGL(transpose_out, dim3(512), dim3(256), 0, stream, ot, out);
}

// Round 14
// 227.114 us; speedup vs baseline: 1.1362x; 1.0502x over previous
//
#include <hip/hip_runtime.h>
#include <stdint.h>

namespace {
constexpr int kB  = 16384;
constexpr int kN  = 128;
constexpr int kI  = 3;
constexpr int kC  = 4;
constexpr int kH  = 90;
constexpr int kL  = 3;
constexpr int BT  = 64;     // batch rows per block (1 wave, 4 n-tiles)
constexpr int KP  = 96;
// A-fragment-contiguous weight tile: 18 frag-blocks (fb=ks*6+mt) x 1024 B.
constexpr int TILE_USH = 18 * 512;
constexpr size_t WT_BYTES = (size_t)4 * kN * TILE_USH * 2;   // 9,437,184
constexpr size_t WO_OFF   = WT_BYTES;                        // float wo[128][96]
constexpr size_t XK_OFF   = WO_OFF + (size_t)kN * KP * 4;    // ushort xk[384][16384]
constexpr size_t OT_OFF   = XK_OFF + (size_t)kN * kI * kB * 2; // float outT[128][16384]
}

typedef __attribute__((ext_vector_type(8))) short bf16x8;
typedef __attribute__((ext_vector_type(4))) float f32x4;

__device__ __forceinline__ uint32_t pack_bf16(float lo, float hi) {
#if __has_builtin(__builtin_amdgcn_cvt_pk_bf16_f32)
  auto r = __builtin_amdgcn_cvt_pk_bf16_f32(lo, hi);
  union { decltype(r) v; uint32_t u; } c; c.v = r; return c.u;
#else
  // round-half-up to bf16 then byte-merge: 3 VALU (add, add, v_perm_b32)
  union { float f; uint32_t i; } a, b; a.f = lo; b.f = hi;
  uint32_t ua = a.i + 0x8000u;
  uint32_t ub = b.i + 0x8000u;
  return __builtin_amdgcn_perm(ub, ua, 0x07060302);  // {ub[3:2], ua[3:2]}
#endif
}
__device__ __forceinline__ ushort f2bf(float f) {
  union { float f; uint32_t i; } v; v.f = f;
  uint32_t u = v.i + 0x7FFFu + ((v.i >> 16) & 1u);
  return (ushort)(u >> 16);
}

// ---- merged preprocess, vectorized emission (round-12, kept) ----
__global__ __launch_bounds__(256) void prep_kernel(
    const float* __restrict__ x,
    const float* __restrict__ W_in, const float* __restrict__ b_in,
    const float* __restrict__ W_hid, const float* __restrict__ b_hid,
    const float* __restrict__ W_out, const float* __restrict__ b_out,
    ushort* __restrict__ wt, float* __restrict__ wo, ushort* __restrict__ xk)
{
  __shared__ float smem[kH * (kH + 1) + kH];
  const int tid = threadIdx.x;
  const int bid = blockIdx.x;

  if (bid < 4 * kN) {          // ---- weight tiles, A-frag-contiguous ----
    float* ldsw = smem;                      // [k][j], stride kH+1 = 91
    float* ldsb = smem + kH * (kH + 1);
    const int node  = bid & (kN - 1);
    const int layer = bid >> 7;
    const int ksrc  = (layer == 0) ? (kI + kC) : kH;
    const float* src;
    const float* bsrc;
    if (layer == 0) { src = W_in + (size_t)node * (kI + kC) * kH; bsrc = b_in + (size_t)node * kH; }
    else {
      int l = layer - 1;
      src  = W_hid + (size_t)(l * kN + node) * kH * kH;
      bsrc = b_hid + (size_t)(l * kN + node) * kH;
    }
    for (int idx = tid; idx < ksrc * kH; idx += 256)
      ldsw[(idx / kH) * (kH + 1) + (idx % kH)] = src[idx];
    if (tid < kH) ldsb[tid] = bsrc[tid];
    __syncthreads();
    ushort* dst = wt + (size_t)bid * TILE_USH;
    const int nch = (layer == 0) ? 384 : 1152;   // 16B chunks (fb*64 + lane)
#pragma unroll
    for (int it = 0; it < 5; ++it) {
      int c = tid + it * 256;
      if (c < nch) {
        int fb = c >> 6, lane = c & 63;
        int mt = fb % 6, ks = fb / 6;
        int j = mt * 16 + (lane & 15);
        int kb = ks * 32 + (lane >> 4) * 8;
        float v[8];
#pragma unroll
        for (int i = 0; i < 8; ++i) {
          int k = kb + i;
          float t = 0.f;
          if (j < kH) {
            if (k < ksrc)       t = ldsw[k * (kH + 1) + j];
            else if (k == ksrc) t = ldsb[j];
          }
          v[i] = t;
        }
        uint4 p;
        p.x = pack_bf16(v[0], v[1]); p.y = pack_bf16(v[2], v[3]);
        p.z = pack_bf16(v[4], v[5]); p.w = pack_bf16(v[6], v[7]);
        *(uint4*)&dst[(size_t)c * 8] = p;
      }
    }
  } else if (bid < 4 * kN + 4) {   // ---- wout float image ----
    int base = (bid - 4 * kN) * 3072;
    for (int t = 0; t < 12; ++t) {
      int idx = base + t * 256 + tid;
      int node = idx / KP, j = idx % KP;
      float v = 0.f;
      if (j < kH)       v = W_out[node * kH + j];
      else if (j == kH) v = b_out[node];
      wo[idx] = v;
    }
  } else {                         // ---- x transpose -> xk[384][16384] bf16 ----
    int xb = bid - (4 * kN + 4);
    int b0 = (xb & 255) * 64;
    int c0 = (xb >> 8) * 96;
    float* lds = smem;             // [64][97]
    for (int idx = tid; idx < 64 * 96; idx += 256) {
      int r = idx / 96, c = idx % 96;
      lds[r * 97 + c] = x[(size_t)(b0 + r) * (kN * kI) + c0 + c];
    }
    __syncthreads();
#pragma unroll
    for (int it = 0; it < 3; ++it) {            // 96 rows x 8 chunks = 768
      int c = tid + it * 256;
      int nk = c >> 3, b = (c & 7) * 8;
      float v[8];
#pragma unroll
      for (int i = 0; i < 8; ++i) v[i] = lds[(b + i) * 97 + nk];
      uint4 p;
      p.x = pack_bf16(v[0], v[1]); p.y = pack_bf16(v[2], v[3]);
      p.z = pack_bf16(v[4], v[5]); p.w = pack_bf16(v[6], v[7]);
      *(uint4*)&xk[(size_t)(c0 + nk) * kB + b0 + b] = p;
    }
  }
}

// ---- main: BT=64, 1 wave/block, barrier-free, launch_bounds(64,3).
// bid = tile*128 + node: with breadth-first dispatch, CU = bid%256 fixes
// node per CU -> resident waves share ONE node's 18KB tile (L1/L2-hot).
// (Round 8-13 had node=bid>>8: resident waves held 128 DIFFERENT tiles ->
// L1 thrash, FETCH = 4x weight image.)
__global__ __launch_bounds__(64, 3) void dnpu_kernel(
    const ushort* __restrict__ xk, const float* __restrict__ controls,
    const ushort* __restrict__ wt, const float* __restrict__ wo,
    float* __restrict__ outT)
{
  __shared__ __align__(16) ushort fbuf[12][BT][8];   // 12,288 B

  const int lane = threadIdx.x;
  const int node = (int)(blockIdx.x & 127);
  const int m0   = (int)(blockIdx.x >> 7) * BT;
  const int quad = lane >> 4;
  const int l16  = lane & 15;

  const f32x4 zf = (f32x4){0.f, 0.f, 0.f, 0.f};      // zero C operand
  f32x4 acc[6][4];

  // ---- layer0 B-frags in registers: only quad==0 lanes non-zero ----
  bf16x8 bfr0[4];
  {
    const ushort cb0 = f2bf(controls[node * kC + 0]);
    const ushort cb1 = f2bf(controls[node * kC + 1]);
    const ushort cb2 = f2bf(controls[node * kC + 2]);
    const ushort cb3 = f2bf(controls[node * kC + 3]);
    if (quad == 0) {
      const ushort* x0p = xk + (size_t)(node * kI + 0) * kB + m0 + l16;
      const ushort* x1p = xk + (size_t)(node * kI + 1) * kB + m0 + l16;
      const ushort* x2p = xk + (size_t)(node * kI + 2) * kB + m0 + l16;
#pragma unroll
      for (int nt = 0; nt < 4; ++nt) {
        union { ushort s[8]; bf16x8 v; } f;
        f.s[0] = x0p[nt * 16]; f.s[1] = x1p[nt * 16]; f.s[2] = x2p[nt * 16];
        f.s[3] = cb0; f.s[4] = cb1; f.s[5] = cb2; f.s[6] = cb3;
        f.s[7] = 0x3F80;                       // 1.0 (bias row k=7)
        bfr0[nt] = f.v;
      }
    } else {
#pragma unroll
      for (int nt = 0; nt < 4; ++nt)
        bfr0[nt] = (bf16x8){0,0,0,0,0,0,0,0};
    }
  }

  // ---- layer0 gemm: C = zf (defined), A-frag streamed per mt ----
  {
    const ushort* tl = wt + (size_t)(0 * kN + node) * TILE_USH;
#pragma unroll
    for (int mt = 0; mt < 6; ++mt) {
      bf16x8 afr = *(const bf16x8*)&tl[(size_t)mt * 512 + lane * 8];
#pragma unroll
      for (int nt = 0; nt < 4; ++nt)
        acc[mt][nt] = __builtin_amdgcn_mfma_f32_16x16x32_bf16(afr, bfr0[nt], zf, 0, 0, 0);
    }
  }

  // relu(acc) -> fbuf (k-major frag layout); j_out==90 := 1.0 (next bias row)
  auto write_h = [&]() {
#pragma unroll
    for (int mt = 0; mt < 6; ++mt) {
      const int kb = 2 * mt + (quad >> 1);
      const int i0 = (quad & 1) * 4;
#pragma unroll
      for (int nt = 0; nt < 4; ++nt) {
        float v0 = fmaxf(acc[mt][nt][0], 0.f);
        float v1 = fmaxf(acc[mt][nt][1], 0.f);
        float v2 = fmaxf(acc[mt][nt][2], 0.f);
        float v3 = fmaxf(acc[mt][nt][3], 0.f);
        if (mt == 5 && quad == 2) v2 = 1.0f;   // j_out = 90
        uint2 p;
        p.x = pack_bf16(v0, v1);
        p.y = pack_bf16(v2, v3);
        *(uint2*)&fbuf[kb][nt * 16 + l16][i0] = p;
      }
    }
  };

#pragma unroll
  for (int l = 0; l < kL; ++l) {
    const ushort* tl = wt + (size_t)((l + 1) * kN + node) * TILE_USH;
    write_h();

    // ks = 0: C = zf (no zero-init of acc), A streamed per mt
    {
      bf16x8 bfr[4];
#pragma unroll
      for (int nt = 0; nt < 4; ++nt)
        bfr[nt] = *(const bf16x8*)&fbuf[quad][nt * 16 + l16][0];
#pragma unroll
      for (int mt = 0; mt < 6; ++mt) {
        bf16x8 afr = *(const bf16x8*)&tl[(size_t)mt * 512 + lane * 8];
#pragma unroll
        for (int nt = 0; nt < 4; ++nt)
          acc[mt][nt] = __builtin_amdgcn_mfma_f32_16x16x32_bf16(afr, bfr[nt], zf, 0, 0, 0);
      }
    }
#pragma unroll
    for (int ks = 1; ks < 3; ++ks) {
      bf16x8 bfr[4];
#pragma unroll
      for (int nt = 0; nt < 4; ++nt)
        bfr[nt] = *(const bf16x8*)&fbuf[ks * 4 + quad][nt * 16 + l16][0];
#pragma unroll
      for (int mt = 0; mt < 6; ++mt) {
        bf16x8 afr = *(const bf16x8*)&tl[(size_t)(ks * 6 + mt) * 512 + lane * 8];
#pragma unroll
        for (int nt = 0; nt < 4; ++nt)
          acc[mt][nt] = __builtin_amdgcn_mfma_f32_16x16x32_bf16(afr, bfr[nt], acc[mt][nt], 0, 0, 0);
      }
    }
  }

  // ---- final dot in registers: out = relu(h3) . wout (+ b_out via j=90) ----
  {
    float4 wof[6];
#pragma unroll
    for (int mt = 0; mt < 6; ++mt)
      wof[mt] = *(const float4*)&wo[node * KP + mt * 16 + quad * 4];
    float s[4] = {0.f, 0.f, 0.f, 0.f};
#pragma unroll
    for (int mt = 0; mt < 6; ++mt) {
#pragma unroll
      for (int nt = 0; nt < 4; ++nt) {
        float h0 = fmaxf(acc[mt][nt][0], 0.f);
        float h1 = fmaxf(acc[mt][nt][1], 0.f);
        float h2 = fmaxf(acc[mt][nt][2], 0.f);
        float h3 = fmaxf(acc[mt][nt][3], 0.f);
        if (mt == 5 && quad == 2) h2 = 1.0f;   // j=90 pairs with wout[90]=b_out
        s[nt] += h0 * wof[mt].x + h1 * wof[mt].y + h2 * wof[mt].z + h3 * wof[mt].w;
      }
    }
#pragma unroll
    for (int nt = 0; nt < 4; ++nt) {
      s[nt] += __shfl_xor(s[nt], 16);
      s[nt] += __shfl_xor(s[nt], 32);
    }
    float r = (quad == 0) ? s[0] : (quad == 1) ? s[1] : (quad == 2) ? s[2] : s[3];
    outT[(size_t)node * kB + m0 + lane] = r;   // lane-linear, 256 B contiguous
  }
}

// ---- outT [128][16384] -> out [16384][128], LDS-tiled, coalesced both sides ----
__global__ __launch_bounds__(256) void transpose_out(
    const float* __restrict__ ot, float* __restrict__ out)
{
  __shared__ float t[64][65];
  const int b0 = (int)(blockIdx.x & 255) * 64;
  const int n0 = (int)(blockIdx.x >> 8) * 64;
  const int c  = threadIdx.x & 63;
  const int r4 = threadIdx.x >> 6;
#pragma unroll
  for (int i = 0; i < 16; ++i) {
    int n = r4 + i * 4;
    t[n][c] = ot[(size_t)(n0 + n) * kB + b0 + c];
  }
  __syncthreads();
#pragma unroll
  for (int i = 0; i < 16; ++i) {
    int b = r4 + i * 4;
    out[(size_t)(b0 + b) * kN + n0 + c] = t[c][b];
  }
}

extern "C" void kernel_launch(void* const* d_in, const int* in_sizes, int n_in,
                              void* d_out, int out_size, void* d_ws, size_t ws_size,
                              hipStream_t stream) {
  const float* x        = (const float*)d_in[0];
  const float* controls = (const float*)d_in[1];
  const float* W_in     = (const float*)d_in[2];
  const float* b_in     = (const float*)d_in[3];
  const float* W_hid    = (const float*)d_in[4];
  const float* b_hid    = (const float*)d_in[5];
  const float* W_out    = (const float*)d_in[6];
  const float* b_out    = (const float*)d_in[7];
  float* out = (float*)d_out;

  ushort* wt = (ushort*)d_ws;
  float*  wo = (float*)((char*)d_ws + WO_OFF);
  ushort* xk = (ushort*)((char*)d_ws + XK_OFF);
  float*  ot = (float*)((char*)d_ws + OT_OFF);

  hipLaunchKernelGGL(prep_kernel, dim3(4 * kN + 4 + 1024), dim3(256), 0, stream,
                     x, W_in, b_in, W_hid, b_hid, W_out, b_out, wt, wo, xk);

  dim3 grid((kB / BT) * kN);   // bid = tile*128 + node -> node fixed per CU
  hipLaunchKernelGGL(dnpu_kernel, grid, dim3(64), 0, stream,
                     xk, controls, wt, wo, ot);

  hipLaunchKernelGGL(transpose_out, dim3(512), dim3(256), 0, stream, ot, out);
}